// Round 4
// baseline (213.968 us; speedup 1.0000x reference)
//
#include <hip/hip_runtime.h>

#define LAMBDA_COORD 5.0f
#define LAMBDA_NOOBJ 0.5f
#define WH_EPS 1e-6f
#define IOU_EPS 1e-6f

// IOU between box a (cx,cy,w,h) and b, matching _iou_yolo exactly.
__device__ __forceinline__ float iou_yolo(float a0, float a1, float a2, float a3,
                                          float b0, float b1, float b2, float b3) {
    float ax1 = a0 - a2 * 0.5f, ay1 = a1 - a3 * 0.5f;
    float ax2 = a0 + a2 * 0.5f, ay2 = a1 + a3 * 0.5f;
    float bx1 = b0 - b2 * 0.5f, by1 = b1 - b3 * 0.5f;
    float bx2 = b0 + b2 * 0.5f, by2 = b1 + b3 * 0.5f;
    float iw = fmaxf(fminf(ax2, bx2) - fmaxf(ax1, bx1), 0.0f);
    float ih = fmaxf(fminf(ay2, by2) - fmaxf(ay1, by1), 0.0f);
    float inter = iw * ih;
    float area_a = fabsf((ax2 - ax1) * (ay2 - ay1));
    float area_b = fabsf((bx2 - bx1) * (by2 - by1));
    return inter / (area_a + area_b - inter + IOU_EPS);
}

// One thread per cell. Cell = 30 floats = 120 B, 8B-aligned -> 15 float2 per
// array. ALL 30 loads are issued before any consumption (independent, no
// aliasing) so each thread keeps ~240 B in flight -> high MLP, no LDS, no
// barriers, no vmcnt(0) convoy. Adjacent threads share cache lines (120 B
// stride vs 64 B lines); L1 absorbs the 2x request aliasing.
__global__ __launch_bounds__(256, 4) void yolo_loss_kernel(
    const float* __restrict__ t_g, const float* __restrict__ p_g,
    float* __restrict__ out, int n_cells, float inv_batch) {
    const int c = blockIdx.x * blockDim.x + threadIdx.x;

    float v = 0.0f;
    if (c < n_cells) {
        const float2* tv = (const float2*)t_g + (size_t)c * 15;
        const float2* pv = (const float2*)p_g + (size_t)c * 15;

        float2 T[15], P[15];
#pragma unroll
        for (int i = 0; i < 15; ++i) T[i] = tv[i];
#pragma unroll
        for (int i = 0; i < 15; ++i) P[i] = pv[i];

        const float b0 = T[0].x, b1 = T[0].y, b2 = T[1].x, b3 = T[1].y, t4 = T[2].x;
        const float p0 = P[0].x, p1 = P[0].y, p2 = P[1].x, p3 = P[1].y, p4 = P[2].x;
        const float p5 = P[2].y, p6 = P[3].x, p7 = P[3].y, p8 = P[4].x, p9 = P[4].y;

        float iou1 = iou_yolo(b0, b1, b2, b3, p0, p1, p2, p3);
        float iou2 = iou_yolo(b0, b1, b2, b3, p5, p6, p7, p8);
        bool use1 = iou1 > iou2;

        float bh0 = use1 ? p0 : p5;
        float bh1 = use1 ? p1 : p6;
        float bh2 = use1 ? p2 : p7;
        float bh3 = use1 ? p3 : p8;
        float conf_c = use1 ? p4 : p9;
        float conf_o = use1 ? p9 : p4;

        float dx = b0 - bh0, dy = b1 - bh1;
        float xy = LAMBDA_COORD * (dx * dx + dy * dy);

        float sw = sqrtf(b2) - sqrtf(fabsf(bh2 + WH_EPS));
        float sh = sqrtf(b3) - sqrtf(fabsf(bh3 + WH_EPS));
        float wh = LAMBDA_COORD * (sw * sw + sh * sh);

        float dc = t4 - conf_c;
        float obj_conf = dc * dc;
        float noobj_in_obj = LAMBDA_NOOBJ * conf_o * conf_o;

        // class SSE: t[10..29] = T[5..14], p[10..29] = P[5..14]
        float cls = 0.0f;
#pragma unroll
        for (int i = 5; i < 15; ++i) {
            float dxc = T[i].x - P[i].x;
            float dyc = T[i].y - P[i].y;
            cls += dxc * dxc + dyc * dyc;
        }

        float obj_terms = xy + wh + obj_conf + noobj_in_obj + cls;

        float d4 = t4 - p4, d9 = t4 - p9;
        float noobj_terms = LAMBDA_NOOBJ * (d4 * d4 + d9 * d9);

        v = (t4 == 1.0f) ? obj_terms : noobj_terms;
    }

    // wave64 reduction -> per-wave LDS -> one atomic per block
#pragma unroll
    for (int off = 32; off > 0; off >>= 1)
        v += __shfl_down(v, off, 64);

    __shared__ float swave[4];
    const int lane = threadIdx.x & 63;
    const int wid = threadIdx.x >> 6;
    if (lane == 0) swave[wid] = v;
    __syncthreads();
    if (threadIdx.x == 0) {
        float s = swave[0] + swave[1] + swave[2] + swave[3];
        atomicAdd(out, s * inv_batch);
    }
}

extern "C" void kernel_launch(void* const* d_in, const int* in_sizes, int n_in,
                              void* d_out, int out_size, void* d_ws, size_t ws_size,
                              hipStream_t stream) {
    const float* t = (const float*)d_in[0];  // y_trues
    const float* p = (const float*)d_in[1];  // y_preds
    float* out = (float*)d_out;

    const int total = in_sizes[0];       // 24,084,480
    const int cells = total / 30;        // 802,816
    const int batch = cells / 49;        // 16,384
    const float inv_batch = 1.0f / (float)batch;

    // d_out is poisoned (0xAA) before every replay — zero it on-stream.
    hipMemsetAsync(out, 0, sizeof(float), stream);

    const int block = 256;
    const int grid = (cells + block - 1) / block;  // 3136
    yolo_loss_kernel<<<grid, block, 0, stream>>>(t, p, out, cells, inv_batch);
}